// Round 23
// baseline (59.423 us; speedup 1.0000x reference)
//
#include <hip/hip_runtime.h>
#include <math.h>

#define H 1024
#define W 1024
#define OH 1016
#define OW 1016
#define BH 16          // output rows per band; 64 bands (last has 8 valid rows)
#define NBANDS 64
#define NCHUNK 5       // chunks advance 248 cols; top 2 lanes = halo providers
#define CSTR 248
#define NIMG 8
#define NWG (NBANDS*NCHUNK*NIMG)   // 2560, divisible by 8 (bijective XCD swizzle)
#define EPS 1e-6f
#define EPS2 1e-12f
#define INV25 (1.0f/25.0f)

// R23 = R15 coop structure + R22's NT stores + ASYNC global->LDS staging.
// Mechanism: register prefetch is compiler-defeated (R19/R20: loads folded
// back to use). global_load_lds CANNOT be folded (dest is LDS, not a reg);
// completion is vmcnt-tracked and waited with a COUNTED s_waitcnt vmcnt(6)
// (newest 6 = next-iter loads just issued; everything older -- this iter's
// loads and last iter's 3 NT stores -- is drained). One full body (~800cyc)
// of compute covers the load latency. Coop per-lane-float4 layout == the
// gload_lds HW layout (wave-uniform base + lane*16). sched_barrier(0)
// around the wait pins ds_reads below it (rule 18) and load-issues above.
// NT stores kept (R22: -9%, FETCH 96->68MB -- inputs stay L2-resident).
// Branchless row clamp for staged rows; tail-band garbage never stored.
// Sentinels: absmax 0.0078125; WRITE = 96774 KB; conflicts ~0.

typedef float vfloat4 __attribute__((ext_vector_type(4)));

__device__ __forceinline__ float4 ld4(const float* p){ return *reinterpret_cast<const float4*>(p); }
__device__ __forceinline__ void st4nt(float* p, float4 v){
    vfloat4 w; w.x = v.x; w.y = v.y; w.z = v.z; w.w = v.w;
    __builtin_nontemporal_store(w, reinterpret_cast<vfloat4*>(p));
}

#define GLOAD_LDS16(g, l)                                                   \
    __builtin_amdgcn_global_load_lds(                                       \
        (const __attribute__((address_space(1))) void*)(g),                 \
        (__attribute__((address_space(3))) void*)(l), 16, 0, 0)

__global__ __launch_bounds__(64, 2)
void yiq_gngc_async(const float* __restrict__ x, const float* __restrict__ y,
                    float* __restrict__ out, long long Nper)
{
    __shared__ __align__(16) float4 ring[5][2][64];    // 10240 B dx/dy ring
    __shared__ __align__(16) float4 stage[2][6][64];   // 12288 B async stage
    const int t = (int)threadIdx.x;

    // ---- XCD-aware bijective swizzle (NWG % 8 == 0) ----
    const int wg  = (int)blockIdx.x;
    const int nid = (wg & 7) * (NWG / 8) + (wg >> 3);
    const int band  = nid % NBANDS;
    const int rest  = nid / NBANDS;
    const int chunk = rest % NCHUNK;
    const int b     = rest / NCHUNK;       // image 0..7

    const int jc = chunk * CSTR;
    const int j0 = jc + 4 * t;
    const int j0L = (j0 > W - 4) ? (W - 4) : j0;       // load clamp (chunk4 tail)
    const bool dostore = (t <= 61) && (j0 <= OW - 4);  // lanes 62,63 halo-only
    const int i0 = band * BH;                          // 0..1008
    const float* xb = x + (size_t)b * (H * W) + j0L;
    const float* yb = y + (size_t)b * (H * W) + j0L;

    float csx[4], csy[4];
    float cp1[8], cp2[8], cp3[8];
    #pragma unroll
    for (int k = 0; k < 4; ++k) { csx[k] = 0.f; csy[k] = 0.f; }
    #pragma unroll
    for (int k = 0; k < 8; ++k) { cp1[k] = 0.f; cp2[k] = 0.f; cp3[k] = 0.f; }

    // ---- initial input column sums over rows i0..i0+4 ----
    #pragma unroll
    for (int r = 0; r < 5; ++r) {
        float4 vx = ld4(xb + (size_t)(i0 + r) * W);
        float4 vy = ld4(yb + (size_t)(i0 + r) * W);
        csx[0] += vx.x; csx[1] += vx.y; csx[2] += vx.z; csx[3] += vx.w;
        csy[0] += vy.x; csy[1] += vy.y; csy[2] += vy.z; csy[3] += vy.w;
    }

    // ---- zero ring slot 4 (the "row -1" subtracted at it=0) ----
    {
        float4 z = make_float4(0.f, 0.f, 0.f, 0.f);
        ring[4][0][t] = z; ring[4][1][t] = z;
    }

    // dx/dy from cs + shfl halo (R15-verified). dn[k] = d at col j0+k.
#define COMPUTE_D(dn, cs, c4)                                              \
    {                                                                      \
        float w4 = __shfl_down(cs[0], 1), w5 = __shfl_down(cs[1], 1);      \
        float w6 = __shfl_down(cs[2], 1), w7 = __shfl_down(cs[3], 1);      \
        float ce2 = __shfl_down(c4.x, 1), ce3 = __shfl_down(c4.y, 1);      \
        float m = cs[1] + cs[2] + cs[3];                                   \
        dn[0] = c4.z - (cs[0] + m + w4) * INV25;                           \
        dn[1] = c4.w - (m + w4 + w5) * INV25;                              \
        dn[2] = ce2 - (cs[2] + cs[3] + w4 + w5 + w6) * INV25;              \
        dn[3] = ce3 - (cs[3] + w4 + w5 + w6 + w7) * INV25;                 \
    }

    // ---- prime dx/dy rows i0..i0+3 into ring slots 0..3 (direct loads) ----
    #pragma unroll
    for (int pr = 0; pr < 4; ++pr) {
        float4 xc = ld4(xb + (size_t)(i0 + pr + 2) * W);
        float4 yc = ld4(yb + (size_t)(i0 + pr + 2) * W);
        float4 nx = ld4(xb + (size_t)(i0 + pr + 5) * W);
        float4 ox = ld4(xb + (size_t)(i0 + pr) * W);
        float4 ny = ld4(yb + (size_t)(i0 + pr + 5) * W);
        float4 oy = ld4(yb + (size_t)(i0 + pr) * W);

        float dxn[4], dyn[4];
        COMPUTE_D(dxn, csx, xc);
        COMPUTE_D(dyn, csy, yc);
        float dhx[4], dhy[4];
        #pragma unroll
        for (int m = 0; m < 4; ++m) { dhx[m] = __shfl_down(dxn[m], 1); dhy[m] = __shfl_down(dyn[m], 1); }

        ring[pr][0][t] = make_float4(dxn[0], dxn[1], dxn[2], dxn[3]);
        ring[pr][1][t] = make_float4(dyn[0], dyn[1], dyn[2], dyn[3]);

        #pragma unroll
        for (int k = 0; k < 4; ++k) {
            cp1[k] += dxn[k] * dyn[k];  cp1[4 + k] += dhx[k] * dhy[k];
            cp2[k] += dxn[k] * dxn[k];  cp2[4 + k] += dhx[k] * dhx[k];
            cp3[k] += dyn[k] * dyn[k];  cp3[4 + k] += dhy[k] * dhy[k];
        }
        csx[0] += nx.x - ox.x; csx[1] += nx.y - ox.y; csx[2] += nx.z - ox.z; csx[3] += nx.w - ox.w;
        csy[0] += ny.x - oy.x; csy[1] += ny.y - oy.y; csy[2] += ny.z - oy.z; csy[3] += ny.w - oy.w;
    }

    float* ob = out + (size_t)b * ((size_t)OH * OW) + j0;
    int s = 4;     // rotating ring slot
    int cur = 0;   // stage buffer holding the CURRENT iteration's rows

    // ---- pre-loop: stage iter-0's rows into stage[0] (rows <= 1017) ----
    GLOAD_LDS16(xb + (size_t)(i0 + 6) * W, &stage[0][0][0]);
    GLOAD_LDS16(yb + (size_t)(i0 + 6) * W, &stage[0][1][0]);
    GLOAD_LDS16(xb + (size_t)(i0 + 9) * W, &stage[0][2][0]);
    GLOAD_LDS16(xb + (size_t)(i0 + 4) * W, &stage[0][3][0]);
    GLOAD_LDS16(yb + (size_t)(i0 + 9) * W, &stage[0][4][0]);
    GLOAD_LDS16(yb + (size_t)(i0 + 4) * W, &stage[0][5][0]);

    // ---- main loop ----
    #pragma unroll 1
    for (int it = 0; it < BH; ++it) {
        const int i = i0 + it;
        if (i >= OH) break;                            // block-uniform (tail band)

        // (1) issue NEXT iteration's 6 loads into stage[cur^1] (rows clamped)
        {
            int rc = i + 7;  rc = rc > H - 1 ? H - 1 : rc;
            int rn = i + 10; rn = rn > H - 1 ? H - 1 : rn;
            int ro = i + 5;  ro = ro > H - 1 ? H - 1 : ro;
            const int nb = cur ^ 1;
            GLOAD_LDS16(xb + (size_t)rc * W, &stage[nb][0][0]);
            GLOAD_LDS16(yb + (size_t)rc * W, &stage[nb][1][0]);
            GLOAD_LDS16(xb + (size_t)rn * W, &stage[nb][2][0]);
            GLOAD_LDS16(xb + (size_t)ro * W, &stage[nb][3][0]);
            GLOAD_LDS16(yb + (size_t)rn * W, &stage[nb][4][0]);
            GLOAD_LDS16(yb + (size_t)ro * W, &stage[nb][5][0]);
        }
        __builtin_amdgcn_sched_barrier(0);
        // (2) counted wait: newest 6 = loads just issued; everything older
        // (this iter's 6 loads + last iter's 3 NT stores) is drained.
        asm volatile("s_waitcnt vmcnt(6)" ::: "memory");
        __builtin_amdgcn_sched_barrier(0);

        // (3) this iteration's rows from LDS stage
        float4 xc = stage[cur][0][t];
        float4 yc = stage[cur][1][t];
        float4 nx = stage[cur][2][t];
        float4 ox = stage[cur][3][t];
        float4 ny = stage[cur][4][t];
        float4 oy = stage[cur][5][t];

        // old dx/dy (row i-1): own 4 from ring (read-before-write, same lane
        // same address -> ordered), halo via shfl (lane63 garbage unstored)
        float4 orx = ring[s][0][t];
        float4 ory = ring[s][1][t];
        float ohx0 = __shfl_down(orx.x, 1), ohx1 = __shfl_down(orx.y, 1);
        float ohx2 = __shfl_down(orx.z, 1), ohx3 = __shfl_down(orx.w, 1);
        float ohy0 = __shfl_down(ory.x, 1), ohy1 = __shfl_down(ory.y, 1);
        float ohy2 = __shfl_down(ory.z, 1), ohy3 = __shfl_down(ory.w, 1);

        // new dx/dy row i+4
        float dxn[4], dyn[4];
        COMPUTE_D(dxn, csx, xc);
        COMPUTE_D(dyn, csy, yc);
        float dhx[4], dhy[4];
        #pragma unroll
        for (int m = 0; m < 4; ++m) { dhx[m] = __shfl_down(dxn[m], 1); dhy[m] = __shfl_down(dyn[m], 1); }

        ring[s][0][t] = make_float4(dxn[0], dxn[1], dxn[2], dxn[3]);
        ring[s][1][t] = make_float4(dyn[0], dyn[1], dyn[2], dyn[3]);

        // slide product column sums: + new row, - old row
        float odx[8] = {orx.x, orx.y, orx.z, orx.w, ohx0, ohx1, ohx2, ohx3};
        float ody[8] = {ory.x, ory.y, ory.z, ory.w, ohy0, ohy1, ohy2, ohy3};
        float ndx[8] = {dxn[0], dxn[1], dxn[2], dxn[3], dhx[0], dhx[1], dhx[2], dhx[3]};
        float ndy[8] = {dyn[0], dyn[1], dyn[2], dyn[3], dhy[0], dhy[1], dhy[2], dhy[3]};
        #pragma unroll
        for (int k = 0; k < 8; ++k) {
            cp1[k] += ndx[k] * ndy[k] - odx[k] * ody[k];
            cp2[k] += ndx[k] * ndx[k] - odx[k] * odx[k];
            cp3[k] += ndy[k] * ndy[k] - ody[k] * ody[k];
        }

        // finalize output row i (rsq path, NT stores)
        if (dostore) {
            float co[4], vv[4], cc[4];
            #pragma unroll
            for (int q = 0; q < 4; ++q) {
                float c_ = (cp1[q] + cp1[q+1] + cp1[q+2] + cp1[q+3] + cp1[q+4]) * INV25;
                float vx = (cp2[q] + cp2[q+1] + cp2[q+2] + cp2[q+3] + cp2[q+4]) * INV25;
                float vy = (cp3[q] + cp3[q+1] + cp3[q+2] + cp3[q+3] + cp3[q+4]) * INV25;
                float sp = vx * vy;
                bool lo  = sp < EPS2;
                float r  = __builtin_amdgcn_rsqf(sp);
                float cr = c_ * r;
                cr = cr < 0.f ? 0.f : (cr > 1.f ? 1.f : cr);
                co[q] = lo ? 0.f : cr;
                vv[q] = lo ? EPS : sp * r;
                cc[q] = lo ? 0.f : c_;
            }
            float* o = ob + (size_t)i * OW;
            st4nt(o,            make_float4(co[0], co[1], co[2], co[3]));
            st4nt(o + Nper,     make_float4(vv[0], vv[1], vv[2], vv[3]));
            st4nt(o + 2 * Nper, make_float4(cc[0], cc[1], cc[2], cc[3]));
        }

        // slide input column sums (unconditional; tail garbage unstored)
        csx[0] += nx.x - ox.x; csx[1] += nx.y - ox.y; csx[2] += nx.z - ox.z; csx[3] += nx.w - ox.w;
        csy[0] += ny.x - oy.x; csy[1] += ny.y - oy.y; csy[2] += ny.z - oy.z; csy[3] += ny.w - oy.w;

        cur ^= 1;
        s = (s == 4) ? 0 : s + 1;
    }
}

extern "C" void kernel_launch(void* const* d_in, const int* in_sizes, int n_in,
                              void* d_out, int out_size, void* d_ws, size_t ws_size,
                              hipStream_t stream) {
    const float* x = (const float*)d_in[0];
    const float* y = (const float*)d_in[1];
    // mask (d_in[2]) unused by the reference's channels==1 path
    float* out = (float*)d_out;
    const long long Nper = (long long)out_size / 3;   // elements per output array
    yiq_gngc_async<<<dim3(NWG), dim3(64), 0, stream>>>(x, y, out, Nper);
}

// Round 24
// 45.306 us; speedup vs baseline: 1.3116x; 1.3116x over previous
//
#include <hip/hip_runtime.h>
#include <math.h>

#define H 1024
#define W 1024
#define OH 1016
#define OW 1016
#define BH 16          // output rows per band; 64 bands (last has 8 valid rows)
#define NBANDS 64
#define NCHUNK 4       // 4 column chunks of 256 output cols
#define NIMG 8
#define NWG (NBANDS*NCHUNK*NIMG)   // 2048, divisible by 8 (bijective XCD swizzle)
#define EPS 1e-6f
#define EPS2 1e-12f    // EPS^2: (vv<EPS) <=> (vx*vy<EPS2)
#define INV25 (1.0f/25.0f)

// FINAL = R22 (best measured: 48.9us, -42% vs baseline 84.5us).
// Structure: R14 sliding-window band kernel + nontemporal output stores.
//  - one wave/block, 4-col lanes, 12-float spans; BH=16 bands; XCD swizzle.
//  - LDS dx/dy ring, read-own-before-write-own (fence-free ordering),
//    halo-4 via __shfl_down, seam lane uses its own rel+4 slot.
//  - rsq finalize (v_rsq_f32); threshold 4.4e-2 >> rsq error.
//  - NT stores: outputs are write-once/never-read; bypassing L2/L3
//    allocation keeps inputs resident (FETCH 96->68MB, dur -9%).
// 23-round synthesis: time invariant under VALU/L1-bytes/LDS/fences/
// conflicts/FETCH/wave-count; register prefetch compiler-folded (R19/R20);
// async gload_lds staging net-negative (R23). This is the source-level
// plateau: traffic at logical floor (166MB), latency-exposed at ~8
// grid-limited waves/CU.
// R5/R9/R12: >~128 live VGPR spills (WRITE sentinel). R6: no sched fences.
// R8: keep XCD swizzle. R11: no raw-row LDS ring.

typedef float vfloat4 __attribute__((ext_vector_type(4)));

__device__ __forceinline__ float4 ld4(const float* p){ return *reinterpret_cast<const float4*>(p); }
__device__ __forceinline__ void st4nt(float* p, float4 v){
    vfloat4 w; w.x = v.x; w.y = v.y; w.z = v.z; w.w = v.w;
    __builtin_nontemporal_store(w, reinterpret_cast<vfloat4*>(p));
}

__device__ __forceinline__ void load12(const float* p, float v[12]) {
    float4 a = ld4(p), b = ld4(p + 4), c = ld4(p + 8);
    v[0]=a.x; v[1]=a.y; v[2]=a.z;  v[3]=a.w;
    v[4]=b.x; v[5]=b.y; v[6]=b.z;  v[7]=b.w;
    v[8]=c.x; v[9]=c.y; v[10]=c.z; v[11]=c.w;
}

__global__ __launch_bounds__(64, 2)
void yiq_gngc_b16nt(const float* __restrict__ x, const float* __restrict__ y,
                    float* __restrict__ out, long long Nper)
{
    __shared__ __align__(16) float ring[5][2][264];   // 10560 B
    const int t = (int)threadIdx.x;

    // ---- XCD-aware bijective swizzle (NWG % 8 == 0) ----
    const int wg  = (int)blockIdx.x;
    const int nid = (wg & 7) * (NWG / 8) + (wg >> 3);
    const int band  = nid % NBANDS;
    const int rest  = nid / NBANDS;        // 0..31
    const int chunk = rest & 3;
    const int b     = rest >> 2;           // image 0..7

    const int jc = chunk * 256;
    const int maxj = (jc + 252 < OW - 4) ? (jc + 252) : (OW - 4);  // 1012 on last chunk
    int j0 = jc + 4 * t; if (j0 > maxj) j0 = maxj;    // clamped lanes duplicate (benign)
    const bool lastlane = (j0 == maxj);               // owns the 4-col ring seam
    const int rel = j0 - jc;                          // 0..252
    const int i0 = band * BH;                         // 0..1008
    const float* xb = x + (size_t)b * (H * W) + j0;
    const float* yb = y + (size_t)b * (H * W) + j0;

    float cs_x[12], cs_y[12];
    float cp1[8], cp2[8], cp3[8];
    #pragma unroll
    for (int k = 0; k < 12; ++k) { cs_x[k] = 0.f; cs_y[k] = 0.f; }
    #pragma unroll
    for (int k = 0; k < 8; ++k) { cp1[k] = 0.f; cp2[k] = 0.f; cp3[k] = 0.f; }

    // ---- zero ring slot 4 (the "row -1" subtracted at it=0) ----
    {
        float4 z = make_float4(0.f, 0.f, 0.f, 0.f);
        *reinterpret_cast<float4*>(&ring[4][0][rel]) = z;
        *reinterpret_cast<float4*>(&ring[4][1][rel]) = z;
        if (lastlane) {
            *reinterpret_cast<float4*>(&ring[4][0][rel + 4]) = z;
            *reinterpret_cast<float4*>(&ring[4][1][rel + 4]) = z;
        }
    }

    // ---- initial input column sums over rows i0..i0+4 (x then y) ----
    #pragma unroll
    for (int r = 0; r < 5; ++r) {
        float vx[12];
        load12(xb + (size_t)(i0 + r) * W, vx);
        #pragma unroll
        for (int k = 0; k < 12; ++k) cs_x[k] += vx[k];
    }
    #pragma unroll
    for (int r = 0; r < 5; ++r) {
        float vy[12];
        load12(yb + (size_t)(i0 + r) * W, vy);
        #pragma unroll
        for (int k = 0; k < 12; ++k) cs_y[k] += vy[k];
    }

    // ---- prime dx/dy rows i0..i0+3 into ring slots 0..3; accumulate cp ----
    // (max row touched: i0+8 = 1016 <= 1023)
    #pragma unroll
    for (int pr = 0; pr < 4; ++pr) {
        float xc[12], yc[12];
        load12(xb + (size_t)(i0 + pr + 2) * W, xc);   // center row
        load12(yb + (size_t)(i0 + pr + 2) * W, yc);
        float dxn[8], dyn[8];
        #pragma unroll
        for (int k = 0; k < 8; ++k) {
            float sx = cs_x[k] + cs_x[k+1] + cs_x[k+2] + cs_x[k+3] + cs_x[k+4];
            float sy = cs_y[k] + cs_y[k+1] + cs_y[k+2] + cs_y[k+3] + cs_y[k+4];
            dxn[k] = xc[k + 2] - sx * INV25;
            dyn[k] = yc[k + 2] - sy * INV25;
            cp1[k] += dxn[k] * dyn[k];
            cp2[k] += dxn[k] * dxn[k];
            cp3[k] += dyn[k] * dyn[k];
        }
        *reinterpret_cast<float4*>(&ring[pr][0][rel]) = make_float4(dxn[0], dxn[1], dxn[2], dxn[3]);
        *reinterpret_cast<float4*>(&ring[pr][1][rel]) = make_float4(dyn[0], dyn[1], dyn[2], dyn[3]);
        if (lastlane) {
            *reinterpret_cast<float4*>(&ring[pr][0][rel + 4]) = make_float4(dxn[4], dxn[5], dxn[6], dxn[7]);
            *reinterpret_cast<float4*>(&ring[pr][1][rel + 4]) = make_float4(dyn[4], dyn[5], dyn[6], dyn[7]);
        }
        // slide cs: add row i0+pr+5, drop row i0+pr (x-pair then y-pair)
        {
            float nx[12], ox[12];
            load12(xb + (size_t)(i0 + pr + 5) * W, nx);
            load12(xb + (size_t)(i0 + pr) * W, ox);
            #pragma unroll
            for (int k = 0; k < 12; ++k) cs_x[k] += nx[k] - ox[k];
        }
        {
            float ny[12], oy[12];
            load12(yb + (size_t)(i0 + pr + 5) * W, ny);
            load12(yb + (size_t)(i0 + pr) * W, oy);
            #pragma unroll
            for (int k = 0; k < 12; ++k) cs_y[k] += ny[k] - oy[k];
        }
    }

    float* ob = out + (size_t)b * ((size_t)OH * OW) + j0;
    int s = 4;   // rotating ring slot (row leaving the window == new row's slot)

    // ---- main loop: output rows i0..i0+BH-1 (tail band breaks at OH) ----
    #pragma unroll 4
    for (int it = 0; it < BH; ++it) {
        const int i = i0 + it;
        if (i >= OH) break;                           // block-uniform (tail band)
        const bool slide = (it < BH - 1) && (i + 1 < OH);  // next iter exists

        // center row for new dx/dy row i+4  (max row 1021)
        float xc[12], yc[12];
        load12(xb + (size_t)(i + 6) * W, xc);
        load12(yb + (size_t)(i + 6) * W, yc);

        // --- old dx/dy (row i-1): own 4 from LDS (same-address as the write
        //     below -> compiler-ordered), halo 4 via shfl from lane t+1 ---
        float4 oox = *reinterpret_cast<float4*>(&ring[s][0][rel]);
        float4 ooy = *reinterpret_cast<float4*>(&ring[s][1][rel]);
        float hx0 = __shfl_down(oox.x, 1), hx1 = __shfl_down(oox.y, 1);
        float hx2 = __shfl_down(oox.z, 1), hx3 = __shfl_down(oox.w, 1);
        float hy0 = __shfl_down(ooy.x, 1), hy1 = __shfl_down(ooy.y, 1);
        float hy2 = __shfl_down(ooy.z, 1), hy3 = __shfl_down(ooy.w, 1);
        if (lastlane) {   // seam lane: halo from its own rel+4 slot (same-address ordered)
            float4 dhx = *reinterpret_cast<float4*>(&ring[s][0][rel + 4]);
            float4 dhy = *reinterpret_cast<float4*>(&ring[s][1][rel + 4]);
            hx0 = dhx.x; hx1 = dhx.y; hx2 = dhx.z; hx3 = dhx.w;
            hy0 = dhy.x; hy1 = dhy.y; hy2 = dhy.z; hy3 = dhy.w;
        }

        // new dx/dy row i+4 (8 halo cols, in registers)
        float dxn[8], dyn[8];
        #pragma unroll
        for (int k = 0; k < 8; ++k) {
            float sx = cs_x[k] + cs_x[k+1] + cs_x[k+2] + cs_x[k+3] + cs_x[k+4];
            float sy = cs_y[k] + cs_y[k+1] + cs_y[k+2] + cs_y[k+3] + cs_y[k+4];
            dxn[k] = xc[k + 2] - sx * INV25;
            dyn[k] = yc[k + 2] - sy * INV25;
        }
        *reinterpret_cast<float4*>(&ring[s][0][rel]) = make_float4(dxn[0], dxn[1], dxn[2], dxn[3]);
        *reinterpret_cast<float4*>(&ring[s][1][rel]) = make_float4(dyn[0], dyn[1], dyn[2], dyn[3]);
        if (lastlane) {
            *reinterpret_cast<float4*>(&ring[s][0][rel + 4]) = make_float4(dxn[4], dxn[5], dxn[6], dxn[7]);
            *reinterpret_cast<float4*>(&ring[s][1][rel + 4]) = make_float4(dyn[4], dyn[5], dyn[6], dyn[7]);
        }

        // slide product column sums: + new row, - old row
        float odx[8] = {oox.x, oox.y, oox.z, oox.w, hx0, hx1, hx2, hx3};
        float ody[8] = {ooy.x, ooy.y, ooy.z, ooy.w, hy0, hy1, hy2, hy3};
        #pragma unroll
        for (int k = 0; k < 8; ++k) {
            cp1[k] += dxn[k] * dyn[k] - odx[k] * ody[k];
            cp2[k] += dxn[k] * dxn[k] - odx[k] * odx[k];
            cp3[k] += dyn[k] * dyn[k] - ody[k] * ody[k];
        }

        // finalize output row i, cols j0..j0+3 (fast rsq path, NT stores)
        float co[4], vv[4], cc[4];
        #pragma unroll
        for (int q = 0; q < 4; ++q) {
            float c_ = (cp1[q] + cp1[q+1] + cp1[q+2] + cp1[q+3] + cp1[q+4]) * INV25;
            float vx = (cp2[q] + cp2[q+1] + cp2[q+2] + cp2[q+3] + cp2[q+4]) * INV25;
            float vy = (cp3[q] + cp3[q+1] + cp3[q+2] + cp3[q+3] + cp3[q+4]) * INV25;
            float sp = vx * vy;
            bool lo  = sp < EPS2;                 // == (sqrt(sp) < EPS); catches sp<0 too
            float r  = __builtin_amdgcn_rsqf(sp); // v_rsq_f32
            float cr = c_ * r;
            cr = cr < 0.f ? 0.f : (cr > 1.f ? 1.f : cr);
            co[q] = lo ? 0.f  : cr;
            vv[q] = lo ? EPS  : sp * r;           // sqrt(sp)
            cc[q] = lo ? 0.f  : c_;
        }
        float* o = ob + (size_t)i * OW;
        st4nt(o,            make_float4(co[0], co[1], co[2], co[3]));
        st4nt(o + Nper,     make_float4(vv[0], vv[1], vv[2], vv[3]));
        st4nt(o + 2 * Nper, make_float4(cc[0], cc[1], cc[2], cc[3]));

        // slide input column sums: add row i+9, drop row i+4 (guarded: i+9<=1023)
        if (slide) {
            {
                float nx[12], oxr[12];
                load12(xb + (size_t)(i + 9) * W, nx);
                load12(xb + (size_t)(i + 4) * W, oxr);
                #pragma unroll
                for (int k = 0; k < 12; ++k) cs_x[k] += nx[k] - oxr[k];
            }
            {
                float ny[12], oyr[12];
                load12(yb + (size_t)(i + 9) * W, ny);
                load12(yb + (size_t)(i + 4) * W, oyr);
                #pragma unroll
                for (int k = 0; k < 12; ++k) cs_y[k] += ny[k] - oyr[k];
            }
        }
        s = (s == 4) ? 0 : s + 1;
    }
}

extern "C" void kernel_launch(void* const* d_in, const int* in_sizes, int n_in,
                              void* d_out, int out_size, void* d_ws, size_t ws_size,
                              hipStream_t stream) {
    const float* x = (const float*)d_in[0];
    const float* y = (const float*)d_in[1];
    // mask (d_in[2]) unused by the reference's channels==1 path
    float* out = (float*)d_out;
    const long long Nper = (long long)out_size / 3;   // elements per output array
    yiq_gngc_b16nt<<<dim3(NWG), dim3(64), 0, stream>>>(x, y, out, Nper);
}